// Round 1
// baseline (57.041 us; speedup 1.0000x reference)
//
#include <hip/hip_runtime.h>
#include <math.h>

// HippoSSKernel (S4 SSKernelDiag forward, ZOH): K[c,h,l] = 2*Re(sum_n Cw[c,h,n]*exp(dtA[h,n]*l))
// Sizes fixed by the problem: H=1024, N=64, CH=1, L=2048.

#define HH  1024
#define NN  64
#define LLEN 2048
#define TPB 256
#define LPT (LLEN / TPB)   // 8 output elements per thread (stride TPB)

__global__ __launch_bounds__(TPB) void sskernel_diag(
    const float* __restrict__ log_dt,      // (H,)
    const float* __restrict__ log_w_real,  // (H,N)
    const float* __restrict__ w_imag,      // (H,N)
    const float* __restrict__ C_re,        // (1,H,N)
    const float* __restrict__ C_im,        // (1,H,N)
    float* __restrict__ out)               // (1,H,L)
{
    __shared__ float s_dar[NN], s_dai[NN];
    __shared__ float s_cwr[NN], s_cwi[NN];
    __shared__ float s_qtr[NN], s_qti[NN];

    const int h = blockIdx.x;
    const int t = threadIdx.x;

    if (t < NN) {
        const int n = t;
        const int idx = h * NN + n;
        const float dtv = expf(log_dt[h]);
        const float wr  = -expf(log_w_real[idx]);
        const float wi  = w_imag[idx];
        const float dar = wr * dtv;            // Re(dtA) < 0
        const float dai = wi * dtv;            // Im(dtA)

        // exp(dtA) = expf(dar) * (cos(dai) + i sin(dai))  (matches jnp complex exp in f32)
        const float em = expf(dar);
        float es, ec;
        sincosf(dai, &es, &ec);
        const float edr = em * ec;
        const float edi = em * es;

        // Cw = C * (exp(dtA) - 1) / w
        const float numr = edr - 1.0f;
        const float numi = edi;
        const float inv  = 1.0f / (wr * wr + wi * wi);
        const float tr = (numr * wr + numi * wi) * inv;
        const float ti = (numi * wr - numr * wi) * inv;
        const float cr = C_re[idx];
        const float ci = C_im[idx];
        s_cwr[n] = cr * tr - ci * ti;
        s_cwi[n] = cr * ti + ci * tr;

        // q^T = exp(dtA * TPB): per-thread stride multiplier
        const float emT = expf(dar * (float)TPB);
        float sT, cT;
        sincosf(dai * (float)TPB, &sT, &cT);
        s_qtr[n] = emT * cT;
        s_qti[n] = emT * sT;

        s_dar[n] = dar;
        s_dai[n] = dai;
    }
    __syncthreads();

    float acc[LPT];
#pragma unroll
    for (int j = 0; j < LPT; ++j) acc[j] = 0.0f;

    const float l0 = (float)t;

    for (int n = 0; n < NN; ++n) {
        const float dar = s_dar[n];
        const float dai = s_dai[n];
        const float cwr = s_cwr[n];
        const float cwi = s_cwi[n];
        const float qtr = s_qtr[n];
        const float qti = s_qti[n];

        // z = exp(dtA * t)
        const float em = expf(dar * l0);
        float sv, cv;
        sincosf(dai * l0, &sv, &cv);
        float zr = em * cv;
        float zi = em * sv;

#pragma unroll
        for (int j = 0; j < LPT; ++j) {
            acc[j] += cwr * zr - cwi * zi;     // Re(Cw * z)
            const float nzr = zr * qtr - zi * qti;
            zi = zr * qti + zi * qtr;
            zr = nzr;
        }
    }

    float* o = out + (size_t)h * LLEN;
#pragma unroll
    for (int j = 0; j < LPT; ++j)
        o[t + j * TPB] = 2.0f * acc[j];
}

extern "C" void kernel_launch(void* const* d_in, const int* in_sizes, int n_in,
                              void* d_out, int out_size, void* d_ws, size_t ws_size,
                              hipStream_t stream) {
    const float* log_dt     = (const float*)d_in[0];
    const float* log_w_real = (const float*)d_in[1];
    const float* w_imag     = (const float*)d_in[2];
    const float* C_re       = (const float*)d_in[3];
    const float* C_im       = (const float*)d_in[4];
    // d_in[5] is L (device int) — sizes are fixed constants for this problem.
    float* out = (float*)d_out;

    sskernel_diag<<<HH, TPB, 0, stream>>>(log_dt, log_w_real, w_imag, C_re, C_im, out);
}

// Round 2
// 28.699 us; speedup vs baseline: 1.9875x; 1.9875x over previous
//
#include <hip/hip_runtime.h>
#include <math.h>

// HippoSSKernel (S4 SSKernelDiag forward, ZOH): K[h,l] = 2*Re(sum_n Cw[h,n]*exp(dtA[h,n]*l))
// H=1024, N=64, CH=1, L=2048.
//
// Strategy: exp(dtA*l) is a geometric sequence in l. Per block (one h), build
// LDS tables by complex squaring from b = exp(dtA) (the ONLY transcendental,
// computed by 64 threads): lo[j]=b^j (j<16), hi'[i]=Cw*b^(16i) (i<32, Cw
// folded), q=b^512. Thread t covers l = t + 512*j via z = hi'[t>>4]*lo[t&15],
// then 3 complex mults by q. No transcendentals in the main loop.

#define HH   1024
#define NN   64
#define LLEN 2048
#define TPB  512
#define LPT  (LLEN / TPB)   // 4

__device__ __forceinline__ float2 cmul(float2 a, float2 b) {
    return make_float2(a.x * b.x - a.y * b.y, a.x * b.y + a.y * b.x);
}

__global__ __launch_bounds__(TPB, 8) void sskernel_diag(
    const float* __restrict__ log_dt,      // (H,)
    const float* __restrict__ log_w_real,  // (H,N)
    const float* __restrict__ w_imag,      // (H,N)
    const float* __restrict__ C_re,        // (1,H,N)
    const float* __restrict__ C_im,        // (1,H,N)
    float* __restrict__ out)               // (1,H,L)
{
    __shared__ float2 s_pow[NN][10];  // b^(2^k), k=0..9
    __shared__ float2 s_cw[NN];       // Cw
    __shared__ float2 s_lo[NN][16];   // b^j
    __shared__ float2 s_hi[NN][32];   // Cw * b^(16*i)
    __shared__ float2 s_q[NN];        // b^512

    const int h = blockIdx.x;
    const int t = threadIdx.x;

    // ---- Phase 1a: 64 threads compute b, Cw, and the squaring chain ----
    if (t < NN) {
        const int n = t;
        const int idx = h * NN + n;
        const float dtv = expf(log_dt[h]);
        const float wr  = -expf(log_w_real[idx]);
        const float wi  = w_imag[idx];
        const float dar = wr * dtv;
        const float dai = wi * dtv;

        const float em = expf(dar);
        float sv, cv;
        sincosf(dai, &sv, &cv);
        float2 b = make_float2(em * cv, em * sv);   // exp(dtA)

        // Cw = C * (b - 1) / w
        const float numr = b.x - 1.0f;
        const float numi = b.y;
        const float inv  = 1.0f / (wr * wr + wi * wi);
        const float tr = (numr * wr + numi * wi) * inv;
        const float ti = (numi * wr - numr * wi) * inv;
        const float cr = C_re[idx];
        const float ci = C_im[idx];
        s_cw[n] = make_float2(cr * tr - ci * ti, cr * ti + ci * tr);

        float2 p = b;
        s_pow[n][0] = p;
#pragma unroll
        for (int k = 1; k < 10; ++k) {
            p = cmul(p, p);             // b^(2^k)
            s_pow[n][k] = p;
        }
    }
    __syncthreads();

    // ---- Phase 1b: build lo/hi/q tables from bit products ----
    // lo[n][j] = b^j, 64*16 = 1024 entries
#pragma unroll
    for (int it = 0; it < 2; ++it) {
        const int e = t + it * TPB;
        const int n = e >> 4, j = e & 15;
        float2 a = make_float2(1.0f, 0.0f);
        if (j & 1) a = cmul(a, s_pow[n][0]);
        if (j & 2) a = cmul(a, s_pow[n][1]);
        if (j & 4) a = cmul(a, s_pow[n][2]);
        if (j & 8) a = cmul(a, s_pow[n][3]);
        s_lo[n][j] = a;
    }
    // hi'[n][i] = Cw[n] * b^(16*i), 64*32 = 2048 entries
#pragma unroll
    for (int it = 0; it < 4; ++it) {
        const int e = t + it * TPB;
        const int n = e >> 5, i = e & 31;
        float2 a = s_cw[n];
        if (i & 1)  a = cmul(a, s_pow[n][4]);
        if (i & 2)  a = cmul(a, s_pow[n][5]);
        if (i & 4)  a = cmul(a, s_pow[n][6]);
        if (i & 8)  a = cmul(a, s_pow[n][7]);
        if (i & 16) a = cmul(a, s_pow[n][8]);
        s_hi[n][i] = a;
    }
    if (t < NN) s_q[t] = s_pow[t][9];   // b^512
    __syncthreads();

    // ---- Phase 2: main accumulation, no transcendentals ----
    const int tlo = t & 15;
    const int thi = t >> 4;

    float acc0 = 0.0f, acc1 = 0.0f, acc2 = 0.0f, acc3 = 0.0f;

    for (int n = 0; n < NN; ++n) {
        const float2 lo = s_lo[n][tlo];
        const float2 hi = s_hi[n][thi];
        const float2 q  = s_q[n];
        float2 z = cmul(hi, lo);        // Cw * exp(dtA * t)
        acc0 += z.x; z = cmul(z, q);
        acc1 += z.x; z = cmul(z, q);
        acc2 += z.x; z = cmul(z, q);
        acc3 += z.x;
    }

    float* o = out + (size_t)h * LLEN;
    o[t          ] = 2.0f * acc0;
    o[t +     TPB] = 2.0f * acc1;
    o[t + 2 * TPB] = 2.0f * acc2;
    o[t + 3 * TPB] = 2.0f * acc3;
}

extern "C" void kernel_launch(void* const* d_in, const int* in_sizes, int n_in,
                              void* d_out, int out_size, void* d_ws, size_t ws_size,
                              hipStream_t stream) {
    const float* log_dt     = (const float*)d_in[0];
    const float* log_w_real = (const float*)d_in[1];
    const float* w_imag     = (const float*)d_in[2];
    const float* C_re       = (const float*)d_in[3];
    const float* C_im       = (const float*)d_in[4];
    float* out = (float*)d_out;

    sskernel_diag<<<HH, TPB, 0, stream>>>(log_dt, log_w_real, w_imag, C_re, C_im, out);
}

// Round 3
// 21.681 us; speedup vs baseline: 2.6310x; 1.3237x over previous
//
#include <hip/hip_runtime.h>
#include <math.h>

// HippoSSKernel (S4 SSKernelDiag forward, ZOH): K[h,l] = 2*Re(sum_n Cw[h,n]*exp(dtA[h,n]*l))
// H=1024, N=64, CH=1, L=2048.
//
// R3 strategy:
//  - thread t (of 256) owns l = t + 256*j, j<8. t = 64*w + lane (wave w, lane = n-index).
//  - term u_j(n) = Re(Cw_n * b_n^t * q_n^j), q = b^256, obeys the REAL 2-term
//    recurrence u_{j+1} = 2Re(q)*u_j - |q|^2*u_{j-1}  (2 FMA/term, no cmul).
//  - per-n constants {2Re(q), -|q|^2, hw=Cw*b^(64w), hw2=hw*q} live in LANE n's
//    registers (wave width 64 == N); broadcast per unrolled n via v_readlane.
//  - only LDS traffic in the main loop: one ds_read_b64 of T[n][lane] = b_n^lane
//    (row-padded to 65 -> conflict-free reads).

#define HH   1024
#define NN   64
#define LLEN 2048
#define TPB  256
#define LPT  (LLEN / TPB)   // 8

__device__ __forceinline__ float2 cmul(float2 a, float2 b) {
    return make_float2(a.x * b.x - a.y * b.y, a.x * b.y + a.y * b.x);
}

__device__ __forceinline__ float rdl(float v, int lane) {
    return __int_as_float(__builtin_amdgcn_readlane(__float_as_int(v), lane));
}

__global__ __launch_bounds__(TPB) void sskernel_diag(
    const float* __restrict__ log_dt,      // (H,)
    const float* __restrict__ log_w_real,  // (H,N)
    const float* __restrict__ w_imag,      // (H,N)
    const float* __restrict__ C_re,        // (1,H,N)
    const float* __restrict__ C_im,        // (1,H,N)
    float* __restrict__ out)               // (1,H,L)
{
    __shared__ float2 s_T[NN][NN + 1];   // T[n][j] = b_n^j, padded row (65)

    const int h    = blockIdx.x;
    const int t    = threadIdx.x;
    const int lane = t & 63;
    const int w    = t >> 6;             // wave index in block (0..3)

    // ---- Prologue: every thread computes n = lane's parameters ----
    const int n   = lane;
    const int idx = h * NN + n;
    const float dtv = expf(log_dt[h]);
    const float wr  = -expf(log_w_real[idx]);
    const float wi  = w_imag[idx];
    const float dar = wr * dtv;
    const float dai = wi * dtv;

    const float em = expf(dar);
    float sv, cv;
    sincosf(dai, &sv, &cv);
    const float2 b = make_float2(em * cv, em * sv);     // exp(dtA)

    // Cw = C * (b - 1) / w
    const float numr = b.x - 1.0f;
    const float numi = b.y;
    const float inv  = 1.0f / (wr * wr + wi * wi);
    const float tr = (numr * wr + numi * wi) * inv;
    const float ti = (numi * wr - numr * wi) * inv;
    const float cr = C_re[idx];
    const float ci = C_im[idx];
    const float2 Cw = make_float2(cr * tr - ci * ti, cr * ti + ci * tr);

    // squaring chain p[k] = b^(2^k), k = 0..8
    float2 p0 = b;
    float2 p1 = cmul(p0, p0);
    float2 p2 = cmul(p1, p1);
    float2 p3 = cmul(p2, p2);
    float2 p4 = cmul(p3, p3);
    float2 p5 = cmul(p4, p4);
    float2 p6 = cmul(p5, p5);
    float2 p7 = cmul(p6, p6);
    float2 p8 = cmul(p7, p7);           // q = b^256

    // lane-resident per-n constants for THIS wave
    const float a_c  = 2.0f * p8.x;                 // 2*Re(q)
    const float b_c  = -(p8.x * p8.x + p8.y * p8.y); // -|q|^2
    float2 hw = Cw;                                  // Cw * b^(64w)
    if (w & 1) hw = cmul(hw, p6);
    if (w & 2) hw = cmul(hw, p7);
    const float2 hw2 = cmul(hw, p8);                 // hw * q

    // fill T[n][16w .. 16w+15] = b^j incrementally from b^(16w)
    float2 e = make_float2(1.0f, 0.0f);
    if (w & 1) e = cmul(e, p4);
    if (w & 2) e = cmul(e, p5);
#pragma unroll
    for (int j2 = 0; j2 < 16; ++j2) {
        s_T[n][16 * w + j2] = e;
        e = cmul(e, b);
    }
    __syncthreads();

    // ---- Main loop: fully unrolled over n; 30 VALU + 1 ds_read_b64 per n ----
    float acc[LPT];
#pragma unroll
    for (int j = 0; j < LPT; ++j) acc[j] = 0.0f;

#pragma unroll
    for (int nn = 0; nn < NN; ++nn) {
        const float2 lo = s_T[nn][lane];            // b_nn^lane
        const float an   = rdl(a_c,  nn);
        const float bn   = rdl(b_c,  nn);
        const float hwx  = rdl(hw.x, nn);
        const float hwy  = rdl(hw.y, nn);
        const float h2x  = rdl(hw2.x, nn);
        const float h2y  = rdl(hw2.y, nn);

        float u0 = fmaf(-hwy, lo.y, hwx * lo.x);    // Re(hw * lo)
        float u1 = fmaf(-h2y, lo.y, h2x * lo.x);    // Re(hw * q * lo)
        acc[0] += u0;
        acc[1] += u1;
#pragma unroll
        for (int j = 2; j < LPT; ++j) {
            const float u = fmaf(an, u1, bn * u0);  // Chebyshev step
            acc[j] += u;
            u0 = u1;
            u1 = u;
        }
    }

    // ---- Epilogue: coalesced stores ----
    float* o = out + (size_t)h * LLEN;
#pragma unroll
    for (int j = 0; j < LPT; ++j)
        o[t + j * TPB] = 2.0f * acc[j];
}

extern "C" void kernel_launch(void* const* d_in, const int* in_sizes, int n_in,
                              void* d_out, int out_size, void* d_ws, size_t ws_size,
                              hipStream_t stream) {
    const float* log_dt     = (const float*)d_in[0];
    const float* log_w_real = (const float*)d_in[1];
    const float* w_imag     = (const float*)d_in[2];
    const float* C_re       = (const float*)d_in[3];
    const float* C_im       = (const float*)d_in[4];
    float* out = (float*)d_out;

    sskernel_diag<<<HH, TPB, 0, stream>>>(log_dt, log_w_real, w_imag, C_re, C_im, out);
}

// Round 4
// 19.223 us; speedup vs baseline: 2.9673x; 1.1278x over previous
//
#include <hip/hip_runtime.h>
#include <math.h>

// HippoSSKernel (S4 SSKernelDiag forward, ZOH): K[h,l] = 2*Re(sum_n Cw[h,n]*exp(dtA[h,n]*l))
// H=1024, N=64, CH=1, L=2048.
//
// R4: same math as R3 (Chebyshev recurrence over j, u_{j+1}=2Re(q)u_j-|q|^2 u_{j-1},
// q=b^256), but per-n constants come from wave-uniform LDS broadcast reads instead
// of v_readlane (kills VALU->SGPR hazards), and the n-loop unroll is capped at 8
// to keep VGPR pressure down (R3 fully unrolled 64x -> suspected spills).

#define HH   1024
#define NN   64
#define LLEN 2048
#define TPB  256
#define LPT  (LLEN / TPB)   // 8

__device__ __forceinline__ float2 cmul(float2 a, float2 b) {
    return make_float2(a.x * b.x - a.y * b.y, a.x * b.y + a.y * b.x);
}

__global__ __launch_bounds__(TPB, 4) void sskernel_diag(
    const float* __restrict__ log_dt,      // (H,)
    const float* __restrict__ log_w_real,  // (H,N)
    const float* __restrict__ w_imag,      // (H,N)
    const float* __restrict__ C_re,        // (1,H,N)
    const float* __restrict__ C_im,        // (1,H,N)
    float* __restrict__ out)               // (1,H,L)
{
    __shared__ float2 s_T[NN][NN + 1];   // [n][j] = b_n^j; pad keeps FILL writes 4-way
    __shared__ float2 s_AB[NN];          // (2*Re(q), -|q|^2)
    __shared__ float4 s_HW[4][NN];       // per wave w: (hw.x, hw.y, hw2.x, hw2.y)

    const int h    = blockIdx.x;
    const int t    = threadIdx.x;
    const int lane = t & 63;
    const int w    = t >> 6;             // wave index (0..3)

    // ---- Prologue: thread (w, lane) computes n = lane's parameters ----
    const int n   = lane;
    const int idx = h * NN + n;
    const float dtv = expf(log_dt[h]);
    const float wr  = -expf(log_w_real[idx]);
    const float wi  = w_imag[idx];
    const float dar = wr * dtv;
    const float dai = wi * dtv;

    const float em = expf(dar);
    float sv, cv;
    sincosf(dai, &sv, &cv);
    const float2 b = make_float2(em * cv, em * sv);     // exp(dtA)

    // Cw2 = 2 * C * (b - 1) / w   (final factor of 2 folded in here)
    const float numr = b.x - 1.0f;
    const float numi = b.y;
    const float inv  = 2.0f / (wr * wr + wi * wi);
    const float tr = (numr * wr + numi * wi) * inv;
    const float ti = (numi * wr - numr * wi) * inv;
    const float cr = C_re[idx];
    const float ci = C_im[idx];
    const float2 Cw2 = make_float2(cr * tr - ci * ti, cr * ti + ci * tr);

    // squaring chain p[k] = b^(2^k)
    const float2 p1 = cmul(b,  b);
    const float2 p2 = cmul(p1, p1);
    const float2 p3 = cmul(p2, p2);
    const float2 p4 = cmul(p3, p3);   // b^16
    const float2 p5 = cmul(p4, p4);   // b^32
    const float2 p6 = cmul(p5, p5);   // b^64
    const float2 p7 = cmul(p6, p6);   // b^128
    const float2 p8 = cmul(p7, p7);   // q = b^256

    if (t < NN)
        s_AB[n] = make_float2(2.0f * p8.x, -(p8.x * p8.x + p8.y * p8.y));

    float2 hw = Cw2;                   // 2*Cw * b^(64w)
    if (w & 1) hw = cmul(hw, p6);
    if (w & 2) hw = cmul(hw, p7);
    const float2 hw2 = cmul(hw, p8);   // hw * q
    s_HW[w][n] = make_float4(hw.x, hw.y, hw2.x, hw2.y);

    // fill T[n][16w .. 16w+15] = b^j from b^(16w)
    float2 e = make_float2(1.0f, 0.0f);
    if (w & 1) e = cmul(e, p4);
    if (w & 2) e = cmul(e, p5);
#pragma unroll
    for (int j2 = 0; j2 < 16; ++j2) {
        s_T[n][16 * w + j2] = e;
        e = cmul(e, b);
    }
    __syncthreads();

    // ---- Main loop: 24 VALU + 3 LDS per n (2 broadcast + 1 conflict-free) ----
    float acc[LPT];
#pragma unroll
    for (int j = 0; j < LPT; ++j) acc[j] = 0.0f;

#pragma unroll 8
    for (int nn = 0; nn < NN; ++nn) {
        const float2 lo  = s_T[nn][lane];   // b_nn^lane, 8B/lane consecutive: free
        const float2 ab  = s_AB[nn];        // uniform -> broadcast
        const float4 hw4 = s_HW[w][nn];     // uniform -> broadcast

        float u0 = fmaf(-hw4.y, lo.y, hw4.x * lo.x);   // Re(hw  * lo)
        float u1 = fmaf(-hw4.w, lo.y, hw4.z * lo.x);   // Re(hw2 * lo)
        acc[0] += u0;
        acc[1] += u1;
#pragma unroll
        for (int j = 2; j < LPT; ++j) {
            const float u = fmaf(ab.x, u1, ab.y * u0); // Chebyshev step
            acc[j] += u;
            u0 = u1;
            u1 = u;
        }
    }

    // ---- Epilogue: coalesced stores (2x already folded into Cw2) ----
    float* o = out + (size_t)h * LLEN;
#pragma unroll
    for (int j = 0; j < LPT; ++j)
        o[t + j * TPB] = acc[j];
}

extern "C" void kernel_launch(void* const* d_in, const int* in_sizes, int n_in,
                              void* d_out, int out_size, void* d_ws, size_t ws_size,
                              hipStream_t stream) {
    const float* log_dt     = (const float*)d_in[0];
    const float* log_w_real = (const float*)d_in[1];
    const float* w_imag     = (const float*)d_in[2];
    const float* C_re       = (const float*)d_in[3];
    const float* C_im       = (const float*)d_in[4];
    float* out = (float*)d_out;

    sskernel_diag<<<HH, TPB, 0, stream>>>(log_dt, log_w_real, w_imag, C_re, C_im, out);
}